// Round 7
// baseline (230.195 us; speedup 1.0000x reference)
//
#include <hip/hip_runtime.h>
#include <hip/hip_bf16.h>

#define NN 8192
#define IND 512
#define OUTD 64
#define ALPHA_ 0.2f
#define LOG2E 1.4426950408889634f

typedef float f32x4 __attribute__((ext_vector_type(4)));
typedef short s16x8 __attribute__((ext_vector_type(8)));
typedef int   i32x4 __attribute__((ext_vector_type(4)));

static __device__ __forceinline__ short f2bf(float x) {
    __hip_bfloat16 b = __float2bfloat16(x);
    return *reinterpret_cast<short*>(&b);
}

// ---- kernel 1: Wh = h@W; Wh1=Wh@a1, Wh2=Wh@a2, whT bf16 [64][8192] ----
__global__ __launch_bounds__(256) void k_wh(const float* __restrict__ h,
                                            const float* __restrict__ W,
                                            const float* __restrict__ a,
                                            __hip_bfloat16* __restrict__ whT,
                                            float* __restrict__ Wh1,
                                            float* __restrict__ Wh2) {
    __shared__ float hs[8 * IND];      // 16 KB
    int tid = threadIdx.x;
    const f32x4* h4 = (const f32x4*)(h + (size_t)blockIdx.x * 8 * IND);
    f32x4* hs4 = (f32x4*)hs;
    #pragma unroll
    for (int t = 0; t < 4; ++t) hs4[tid + t * 256] = h4[tid + t * 256];
    __syncthreads();

    int w = tid >> 6, l = tid & 63;
    int g = l >> 4, lc = l & 15;
    int c4 = lc * 4;
    const float* hrow = hs + (w * 2) * IND;
    f32x4 acc0 = {0.f, 0.f, 0.f, 0.f};
    f32x4 acc1 = {0.f, 0.f, 0.f, 0.f};

    #pragma unroll 4
    for (int k0 = 0; k0 < 128; ++k0) {
        int k = k0 * 4 + g;
        f32x4 wv = *(const f32x4*)(W + k * OUTD + c4);
        float h0 = hrow[k];
        float h1 = hrow[IND + k];
        acc0[0] = fmaf(h0, wv[0], acc0[0]);
        acc0[1] = fmaf(h0, wv[1], acc0[1]);
        acc0[2] = fmaf(h0, wv[2], acc0[2]);
        acc0[3] = fmaf(h0, wv[3], acc0[3]);
        acc1[0] = fmaf(h1, wv[0], acc1[0]);
        acc1[1] = fmaf(h1, wv[1], acc1[1]);
        acc1[2] = fmaf(h1, wv[2], acc1[2]);
        acc1[3] = fmaf(h1, wv[3], acc1[3]);
    }

    #pragma unroll
    for (int e = 0; e < 4; ++e) {
        acc0[e] += __shfl_xor(acc0[e], 16, 64);
        acc0[e] += __shfl_xor(acc0[e], 32, 64);
        acc1[e] += __shfl_xor(acc1[e], 16, 64);
        acc1[e] += __shfl_xor(acc1[e], 32, 64);
    }

    int row0 = blockIdx.x * 8 + w * 2;
    if (g == 0) {
        #pragma unroll
        for (int e = 0; e < 4; ++e) {
            whT[(size_t)(c4 + e) * NN + row0]     = __float2bfloat16(acc0[e]);
            whT[(size_t)(c4 + e) * NN + row0 + 1] = __float2bfloat16(acc1[e]);
        }
    }

    float p10 = 0.f, p20 = 0.f, p11 = 0.f, p21 = 0.f;
    #pragma unroll
    for (int e = 0; e < 4; ++e) {
        float a1 = a[c4 + e], a2 = a[OUTD + c4 + e];
        p10 = fmaf(acc0[e], a1, p10);
        p20 = fmaf(acc0[e], a2, p20);
        p11 = fmaf(acc1[e], a1, p11);
        p21 = fmaf(acc1[e], a2, p21);
    }
    #pragma unroll
    for (int off = 1; off < 16; off <<= 1) {
        p10 += __shfl_xor(p10, off, 64);
        p20 += __shfl_xor(p20, off, 64);
        p11 += __shfl_xor(p11, off, 64);
        p21 += __shfl_xor(p21, off, 64);
    }
    if (l == 0) {
        Wh1[row0] = p10;     Wh2[row0] = p20;
        Wh1[row0 + 1] = p11; Wh2[row0 + 1] = p21;
    }
}

// ---- kernel 1b: mx = max_j Wh2[j] ----
__global__ __launch_bounds__(256) void k_max(const float* __restrict__ Wh2,
                                             float* __restrict__ mx) {
    float m = -1e30f;
    for (int i = threadIdx.x; i < NN; i += 256) m = fmaxf(m, Wh2[i]);
    #pragma unroll
    for (int off = 1; off < 64; off <<= 1) m = fmaxf(m, __shfl_xor(m, off, 64));
    __shared__ float sm[4];
    if ((threadIdx.x & 63) == 0) sm[threadIdx.x >> 6] = m;
    __syncthreads();
    if (threadIdx.x == 0) *mx = fmaxf(fmaxf(sm[0], sm[1]), fmaxf(sm[2], sm[3]));
}

// ---- kernel 2: fused mask+softmax+PV. 16 rows/block, 8 waves split j. ----
__global__ __launch_bounds__(512) void k_gat(const int* __restrict__ adj,
                                             const __hip_bfloat16* __restrict__ whT,
                                             const float* __restrict__ Wh1,
                                             const float* __restrict__ Wh2,
                                             const float* __restrict__ mxp,
                                             float* __restrict__ out) {
    int tid = threadIdx.x;
    int w   = tid >> 6;        // wave 0..7
    int l   = tid & 63;
    int lr  = l & 15;          // A-row / B-col within 16-tile
    int grp = l >> 4;          // k-group (8 consecutive j per lane)
    int ib  = blockIdx.x * 16;
    int row = ib + lr;

    float wh1r = Wh1[row];
    float mi = wh1r + *mxp;            // upper bound on row max of e (leakyrelu monotone)
    mi = fmaxf(mi, ALPHA_ * mi);
    float mc = mi * LOG2E;

    f32x4 acc0 = {0.f, 0.f, 0.f, 0.f};
    f32x4 acc1 = acc0, acc2 = acc0, acc3 = acc0;
    float lsum = 0.f;

    const int* ap = adj + (size_t)row * NN;
    const __hip_bfloat16* bp = whT + (size_t)lr * NN;
    int jbase = w * 32 + grp * 8;

#define LOADJ(J, AV0, AV1, W20, W21, B0, B1, B2, B3)           \
    AV0 = *(const i32x4*)(ap + (J));                           \
    AV1 = *(const i32x4*)(ap + (J) + 4);                       \
    W20 = *(const f32x4*)(Wh2 + (J));                          \
    W21 = *(const f32x4*)(Wh2 + (J) + 4);                      \
    B0  = *(const s16x8*)(bp + (J));                           \
    B1  = *(const s16x8*)(bp + (size_t)16 * NN + (J));         \
    B2  = *(const s16x8*)(bp + (size_t)32 * NN + (J));         \
    B3  = *(const s16x8*)(bp + (size_t)48 * NN + (J));

    i32x4 av0, av1;
    f32x4 w20, w21;
    s16x8 b0, b1, b2, b3;
    LOADJ(jbase, av0, av1, w20, w21, b0, b1, b2, b3)

    for (int it = 0; it < 32; ++it) {
        i32x4 nav0, nav1;
        f32x4 nw20, nw21;
        s16x8 nb0, nb1, nb2, nb3;
        if (it < 31) {
            int jn = (it + 1) * 256 + jbase;
            LOADJ(jn, nav0, nav1, nw20, nw21, nb0, nb1, nb2, nb3)
        }

        s16x8 af;
        #pragma unroll
        for (int e = 0; e < 4; ++e) {
            float x = wh1r + w20[e];
            x = fmaxf(x, ALPHA_ * x);                  // leaky relu
            float p = exp2f(fmaf(x, LOG2E, -mc));      // exp(x - mi)
            p = (av0[e] > 0) ? p : 0.f;                // adjacency mask
            lsum += p;
            af[e] = f2bf(p);
        }
        #pragma unroll
        for (int e = 0; e < 4; ++e) {
            float x = wh1r + w21[e];
            x = fmaxf(x, ALPHA_ * x);
            float p = exp2f(fmaf(x, LOG2E, -mc));
            p = (av1[e] > 0) ? p : 0.f;
            lsum += p;
            af[e + 4] = f2bf(p);
        }
        acc0 = __builtin_amdgcn_mfma_f32_16x16x32_bf16(af, b0, acc0, 0, 0, 0);
        acc1 = __builtin_amdgcn_mfma_f32_16x16x32_bf16(af, b1, acc1, 0, 0, 0);
        acc2 = __builtin_amdgcn_mfma_f32_16x16x32_bf16(af, b2, acc2, 0, 0, 0);
        acc3 = __builtin_amdgcn_mfma_f32_16x16x32_bf16(af, b3, acc3, 0, 0, 0);

        if (it < 31) {
            av0 = nav0; av1 = nav1;
            w20 = nw20; w21 = nw21;
            b0 = nb0; b1 = nb1; b2 = nb2; b3 = nb3;
        }
    }
#undef LOADJ

    // denominator: sum across the 4 k-groups (lanes xor 16/32)
    lsum += __shfl_xor(lsum, 16, 64);
    lsum += __shfl_xor(lsum, 32, 64);

    // cross-wave combine via LDS
    __shared__ float lacc[8][16][65];
    __shared__ float lls[8][16];
    #pragma unroll
    for (int reg = 0; reg < 4; ++reg) {
        int rr = grp * 4 + reg;           // C layout: row=(lane>>4)*4+reg, col=lane&15
        lacc[w][rr][lr]      = acc0[reg];
        lacc[w][rr][16 + lr] = acc1[reg];
        lacc[w][rr][32 + lr] = acc2[reg];
        lacc[w][rr][48 + lr] = acc3[reg];
    }
    if (l < 16) lls[w][l] = lsum;
    __syncthreads();

    #pragma unroll
    for (int t = 0; t < 2; ++t) {
        int idx = tid + t * 512;          // 1024 outputs: 16 rows x 64 cols
        int rr = idx >> 6, c = idx & 63;
        float v = 0.f, ls = 0.f;
        #pragma unroll
        for (int ww = 0; ww < 8; ++ww) {
            v += lacc[ww][rr][c];
            ls += lls[ww][rr];
        }
        float hv = v / ls;
        out[(size_t)(ib + rr) * OUTD + c] = hv > 0.f ? hv : exp2f(hv * LOG2E) - 1.f;
    }
}

extern "C" void kernel_launch(void* const* d_in, const int* in_sizes, int n_in,
                              void* d_out, int out_size, void* d_ws, size_t ws_size,
                              hipStream_t stream) {
    const float* h   = (const float*)d_in[0];
    const int*   adj = (const int*)d_in[1];
    const float* W   = (const float*)d_in[2];
    const float* a   = (const float*)d_in[3];
    float* out = (float*)d_out;

    char* ws = (char*)d_ws;
    __hip_bfloat16*  whT = (__hip_bfloat16*)ws;                      // 1 MB
    float*           Wh1 = (float*)(ws + 1048576);                   // 32 KB
    float*           Wh2 = Wh1 + NN;                                 // 32 KB
    float*           mx  = Wh2 + NN;                                 // 4 B

    k_wh<<<NN / 8, 256, 0, stream>>>(h, W, a, whT, Wh1, Wh2);
    k_max<<<1, 256, 0, stream>>>(Wh2, mx);
    // ATTRIBUTION ROUND: k_gat launched TWICE (idempotent — identical writes).
    // dur_total = (k_wh + k_max + k_gat) + k_gat  =>  k_gat = dur_total - 133us (R3 baseline).
    k_gat<<<NN / 16, 512, 0, stream>>>(adj, whT, Wh1, Wh2, mx, out);
    k_gat<<<NN / 16, 512, 0, stream>>>(adj, whT, Wh1, Wh2, mx, out);
}

// Round 8
// 162.453 us; speedup vs baseline: 1.4170x; 1.4170x over previous
//
#include <hip/hip_runtime.h>
#include <hip/hip_bf16.h>

#define NN 8192
#define IND 512
#define OUTD 64
#define ALPHA_ 0.2f
#define LOG2E 1.4426950408889634f

typedef float f32x4 __attribute__((ext_vector_type(4)));
typedef short s16x8 __attribute__((ext_vector_type(8)));
typedef int   i32x4 __attribute__((ext_vector_type(4)));
typedef unsigned int uint;

static __device__ __forceinline__ short f2bf(float x) {
    __hip_bfloat16 b = __float2bfloat16(x);
    return *reinterpret_cast<short*>(&b);
}
static __device__ __forceinline__ uint fenc(float f) {
    uint u = __float_as_uint(f);
    return (u & 0x80000000u) ? ~u : (u | 0x80000000u);
}
static __device__ __forceinline__ float fdec(uint k) {
    uint u = (k & 0x80000000u) ? (k & 0x7FFFFFFFu) : ~k;
    return __uint_as_float(u);
}

// ---- kernel 1: Wh = h@W; whT bf16 [64][8192]; Wh1s/Wh2s prescaled by log2e; atomic max ----
__global__ __launch_bounds__(256) void k_wh(const float* __restrict__ h,
                                            const float* __restrict__ W,
                                            const float* __restrict__ a,
                                            __hip_bfloat16* __restrict__ whT,
                                            float* __restrict__ Wh1s,
                                            float* __restrict__ Wh2s,
                                            uint* __restrict__ mxk) {
    __shared__ float hs[8 * IND];      // 16 KB
    int tid = threadIdx.x;
    const f32x4* h4 = (const f32x4*)(h + (size_t)blockIdx.x * 8 * IND);
    f32x4* hs4 = (f32x4*)hs;
    #pragma unroll
    for (int t = 0; t < 4; ++t) hs4[tid + t * 256] = h4[tid + t * 256];
    __syncthreads();

    int w = tid >> 6, l = tid & 63;
    int g = l >> 4, lc = l & 15;
    int c4 = lc * 4;
    const float* hrow = hs + (w * 2) * IND;
    f32x4 acc0 = {0.f, 0.f, 0.f, 0.f};
    f32x4 acc1 = {0.f, 0.f, 0.f, 0.f};

    #pragma unroll 4
    for (int k0 = 0; k0 < 128; ++k0) {
        int k = k0 * 4 + g;
        f32x4 wv = *(const f32x4*)(W + k * OUTD + c4);
        float h0 = hrow[k];
        float h1 = hrow[IND + k];
        acc0[0] = fmaf(h0, wv[0], acc0[0]);
        acc0[1] = fmaf(h0, wv[1], acc0[1]);
        acc0[2] = fmaf(h0, wv[2], acc0[2]);
        acc0[3] = fmaf(h0, wv[3], acc0[3]);
        acc1[0] = fmaf(h1, wv[0], acc1[0]);
        acc1[1] = fmaf(h1, wv[1], acc1[1]);
        acc1[2] = fmaf(h1, wv[2], acc1[2]);
        acc1[3] = fmaf(h1, wv[3], acc1[3]);
    }

    #pragma unroll
    for (int e = 0; e < 4; ++e) {
        acc0[e] += __shfl_xor(acc0[e], 16, 64);
        acc0[e] += __shfl_xor(acc0[e], 32, 64);
        acc1[e] += __shfl_xor(acc1[e], 16, 64);
        acc1[e] += __shfl_xor(acc1[e], 32, 64);
    }

    int row0 = blockIdx.x * 8 + w * 2;
    if (g == 0) {
        #pragma unroll
        for (int e = 0; e < 4; ++e) {
            whT[(size_t)(c4 + e) * NN + row0]     = __float2bfloat16(acc0[e]);
            whT[(size_t)(c4 + e) * NN + row0 + 1] = __float2bfloat16(acc1[e]);
        }
    }

    float p10 = 0.f, p20 = 0.f, p11 = 0.f, p21 = 0.f;
    #pragma unroll
    for (int e = 0; e < 4; ++e) {
        float a1 = a[c4 + e], a2 = a[OUTD + c4 + e];
        p10 = fmaf(acc0[e], a1, p10);
        p20 = fmaf(acc0[e], a2, p20);
        p11 = fmaf(acc1[e], a1, p11);
        p21 = fmaf(acc1[e], a2, p21);
    }
    #pragma unroll
    for (int off = 1; off < 16; off <<= 1) {
        p10 += __shfl_xor(p10, off, 64);
        p20 += __shfl_xor(p20, off, 64);
        p11 += __shfl_xor(p11, off, 64);
        p21 += __shfl_xor(p21, off, 64);
    }
    if (l == 0) {
        float s20 = p20 * LOG2E, s21 = p21 * LOG2E;
        Wh1s[row0]     = p10 * LOG2E;  Wh2s[row0]     = s20;
        Wh1s[row0 + 1] = p11 * LOG2E;  Wh2s[row0 + 1] = s21;
        atomicMax(mxk, fenc(fmaxf(s20, s21)));
    }
}

#define MFMA_BF16 __builtin_amdgcn_mfma_f32_16x16x32_bf16

// p-compute: 8 masked softmax numerators from two i32x4 + two f32x4
#define PCOMP(V0, V1, W0, W1, WH1, MC, LS, POUT) { \
    _Pragma("unroll") \
    for (int e = 0; e < 4; ++e) { \
        float t_ = (WH1) + (W0)[e]; \
        float x_ = fmaxf(t_, ALPHA_ * t_); \
        float p_ = exp2f(x_ - (MC)); \
        p_ = ((V0)[e] != 0) ? p_ : 0.f; \
        (LS) += p_; (POUT)[e] = f2bf(p_); \
    } \
    _Pragma("unroll") \
    for (int e = 0; e < 4; ++e) { \
        float t_ = (WH1) + (W1)[e]; \
        float x_ = fmaxf(t_, ALPHA_ * t_); \
        float p_ = exp2f(x_ - (MC)); \
        p_ = ((V1)[e] != 0) ? p_ : 0.f; \
        (LS) += p_; (POUT)[e + 4] = f2bf(p_); \
    } }

// ---- kernel 2: fused GAT. Wave streams 2 adj rows coalesced -> p -> LDS P-tile;
// MFMA phase reads swizzled A-frags from LDS, B-frags from L2-resident whT. ----
__global__ __launch_bounds__(512, 4) void k_gat(const int* __restrict__ adj,
                                                const __hip_bfloat16* __restrict__ whT,
                                                const float* __restrict__ Wh1s,
                                                const float* __restrict__ Wh2s,
                                                const uint* __restrict__ mxk,
                                                float* __restrict__ out) {
    __shared__ __align__(16) char smem[33408];   // P[2][16][512]bf16 (32KB) | lacc(33280)+lls(64)
    __hip_bfloat16 (*P)[16][512] = (__hip_bfloat16 (*)[16][512])smem;

    int tid = threadIdx.x;
    int w   = tid >> 6;        // wave 0..7
    int l   = tid & 63;
    int lr  = l & 15;
    int grp = l >> 4;
    int ib  = blockIdx.x * 16;
    int ra  = 2 * w, rb = 2 * w + 1;    // rows this wave stages

    float mxv  = fdec(*mxk);
    float wh1a = Wh1s[ib + ra];
    float wh1b = Wh1s[ib + rb];
    float ta = wh1a + mxv, tb = wh1b + mxv;
    float mca = fmaxf(ta, ALPHA_ * ta);          // per-row softmax upper bound (scaled)
    float mcb = fmaxf(tb, ALPHA_ * tb);

    const int*   apa = adj + (size_t)(ib + ra) * NN + 8 * l;   // lane-contiguous 8 ints
    const int*   apb = adj + (size_t)(ib + rb) * NN + 8 * l;
    const float* wp  = Wh2s + 8 * l;

    float lsa = 0.f, lsb = 0.f;
    i32x4 va0, va1, vb0, vb1;
    f32x4 w20, w21;
    s16x8 pa, pb;

    // prologue: stage chunk 0 into buf 0
    va0 = *(const i32x4*)(apa);
    va1 = *(const i32x4*)(apa + 4);
    vb0 = *(const i32x4*)(apb);
    vb1 = *(const i32x4*)(apb + 4);
    w20 = *(const f32x4*)(wp);
    w21 = *(const f32x4*)(wp + 4);
    PCOMP(va0, va1, w20, w21, wh1a, mca, lsa, pa)
    PCOMP(vb0, vb1, w20, w21, wh1b, mcb, lsb, pb)
    *(s16x8*)&P[0][ra][(l ^ (ra & 7)) << 3] = pa;   // XOR-swizzled 8-elem blocks
    *(s16x8*)&P[0][rb][(l ^ (rb & 7)) << 3] = pb;
    __syncthreads();

    f32x4 acc0 = {0.f, 0.f, 0.f, 0.f};
    f32x4 acc1 = acc0, acc2 = acc0, acc3 = acc0;
    const __hip_bfloat16* bp = whT + (size_t)lr * NN;

    for (int c = 0; c < 16; ++c) {
        int cur = c & 1;
        // A-frags (LDS, swizzled): wave w K-slice = [w*64, w*64+64)
        s16x8 a0 = *(const s16x8*)&P[cur][lr][((((w << 3)     + grp)) ^ (lr & 7)) << 3];
        s16x8 a1 = *(const s16x8*)&P[cur][lr][((((w << 3) + 4 + grp)) ^ (lr & 7)) << 3];
        // B-frags FIRST (vmcnt retires in issue order: keep fast L2 loads ahead of HBM batch)
        size_t jb = (size_t)c * 512 + w * 64 + grp * 8;
        s16x8 b00 = *(const s16x8*)(bp + jb);
        s16x8 b01 = *(const s16x8*)(bp + (size_t)16 * NN + jb);
        s16x8 b02 = *(const s16x8*)(bp + (size_t)32 * NN + jb);
        s16x8 b03 = *(const s16x8*)(bp + (size_t)48 * NN + jb);
        s16x8 b10 = *(const s16x8*)(bp + jb + 32);
        s16x8 b11 = *(const s16x8*)(bp + (size_t)16 * NN + jb + 32);
        s16x8 b12 = *(const s16x8*)(bp + (size_t)32 * NN + jb + 32);
        s16x8 b13 = *(const s16x8*)(bp + (size_t)48 * NN + jb + 32);
        // early-issue next adj chunk (HBM); consumed after MFMAs -> latency hidden
        if (c < 15) {
            int off = (c + 1) * 512;
            va0 = *(const i32x4*)(apa + off);
            va1 = *(const i32x4*)(apa + off + 4);
            vb0 = *(const i32x4*)(apb + off);
            vb1 = *(const i32x4*)(apb + off + 4);
            w20 = *(const f32x4*)(wp + off);
            w21 = *(const f32x4*)(wp + off + 4);
        }
        __builtin_amdgcn_sched_barrier(0);   // pin: loads above, MFMAs below
        acc0 = MFMA_BF16(a0, b00, acc0, 0, 0, 0);
        acc1 = MFMA_BF16(a0, b01, acc1, 0, 0, 0);
        acc2 = MFMA_BF16(a0, b02, acc2, 0, 0, 0);
        acc3 = MFMA_BF16(a0, b03, acc3, 0, 0, 0);
        acc0 = MFMA_BF16(a1, b10, acc0, 0, 0, 0);
        acc1 = MFMA_BF16(a1, b11, acc1, 0, 0, 0);
        acc2 = MFMA_BF16(a1, b12, acc2, 0, 0, 0);
        acc3 = MFMA_BF16(a1, b13, acc3, 0, 0, 0);
        __builtin_amdgcn_sched_barrier(0);   // keep vmcnt(0) wait (p-compute) after MFMAs
        if (c < 15) {
            PCOMP(va0, va1, w20, w21, wh1a, mca, lsa, pa)
            PCOMP(vb0, vb1, w20, w21, wh1b, mcb, lsb, pb)
            int nxt = cur ^ 1;
            *(s16x8*)&P[nxt][ra][(l ^ (ra & 7)) << 3] = pa;
            *(s16x8*)&P[nxt][rb][(l ^ (rb & 7)) << 3] = pb;
        }
        __syncthreads();
    }

    // denominators: full-wave reduce of this wave's 2 rows
    #pragma unroll
    for (int off = 1; off < 64; off <<= 1) {
        lsa += __shfl_xor(lsa, off, 64);
        lsb += __shfl_xor(lsb, off, 64);
    }

    // cross-wave combine (reuse smem; loop's final barrier fenced all P reads)
    float (*lacc)[16][65] = (float (*)[16][65])smem;
    float* lls = (float*)(smem + 33280);
    #pragma unroll
    for (int reg = 0; reg < 4; ++reg) {
        int rr = grp * 4 + reg;            // C layout: row=(lane>>4)*4+reg, col=lane&15
        lacc[w][rr][lr]      = acc0[reg];
        lacc[w][rr][16 + lr] = acc1[reg];
        lacc[w][rr][32 + lr] = acc2[reg];
        lacc[w][rr][48 + lr] = acc3[reg];
    }
    if (l == 0) { lls[ra] = lsa; lls[rb] = lsb; }
    __syncthreads();

    #pragma unroll
    for (int t = 0; t < 2; ++t) {
        int idx = tid + t * 512;           // 1024 outputs: 16 rows x 64 cols
        int rr = idx >> 6, cc = idx & 63;
        float v = 0.f;
        #pragma unroll
        for (int ww = 0; ww < 8; ++ww) v += lacc[ww][rr][cc];
        float hv = v / lls[rr];
        out[(size_t)(ib + rr) * OUTD + cc] = hv > 0.f ? hv : exp2f(hv * LOG2E) - 1.f;
    }
}

extern "C" void kernel_launch(void* const* d_in, const int* in_sizes, int n_in,
                              void* d_out, int out_size, void* d_ws, size_t ws_size,
                              hipStream_t stream) {
    const float* h   = (const float*)d_in[0];
    const int*   adj = (const int*)d_in[1];
    const float* W   = (const float*)d_in[2];
    const float* a   = (const float*)d_in[3];
    float* out = (float*)d_out;

    char* ws = (char*)d_ws;
    __hip_bfloat16*  whT  = (__hip_bfloat16*)ws;                     // 1 MB
    float*           Wh1s = (float*)(ws + 1048576);                  // 32 KB
    float*           Wh2s = Wh1s + NN;                               // 32 KB
    uint*            mxk  = (uint*)(Wh2s + NN);                      // 4 B

    hipMemsetAsync(mxk, 0, 4, stream);     // encoded -inf identity (all encodings > 0)
    k_wh<<<NN / 8, 256, 0, stream>>>(h, W, a, whT, Wh1s, Wh2s, mxk);
    k_gat<<<NN / 16, 512, 0, stream>>>(adj, whT, Wh1s, Wh2s, mxk, out);
}